// Round 4
// baseline (63656.000 us; speedup 1.0000x reference)
//
#include <hip/hip_runtime.h>
#include <hip/hip_bf16.h>

typedef __hip_bfloat16 bf16;

constexpr int BB  = 64;
constexpr int TT  = 351;
constexpr int DD  = 512;
constexpr int HH  = 8;
constexpr int DK  = 64;
constexpr int FF  = 1024;
constexpr int LL  = 3;
constexpr int MT  = BB * TT;      // 22464
constexpr int TD  = TT * DD;

constexpr int CHA = 8;            // batches per attention chunk
constexpr int MA  = CHA * TT;     // 2808
constexpr int NCA = BB / CHA;     // 8
constexpr int CHF = 16;           // batches per FFN chunk
constexpr int MF  = CHF * TT;     // 5616
constexpr int NCF = BB / CHF;     // 4

__device__ __forceinline__ float us2f(unsigned short u) {
    union { unsigned int i; float f; } c; c.i = ((unsigned int)u) << 16; return c.f;
}
__device__ __forceinline__ float bf2f(bf16 h) { return __bfloat162float(h); }
__device__ __forceinline__ bf16  f2bf(float f) { return __float2bfloat16(f); }
// load element i of a raw input buffer whose dtype is fp32 (f32=true) or bf16
__device__ __forceinline__ float ldin(const void* p, size_t i, bool f32) {
    return f32 ? ((const float*)p)[i] : bf2f(((const bf16*)p)[i]);
}

// ---------------------------------------------------------------------------
// dtype detect: ln1_a is all-ones. fp32 1.0f low u16 = 0x0000; bf16 1.0=0x3F80
// ---------------------------------------------------------------------------
__global__ void detect_kernel(const unsigned short* ln1a, int* flag) {
    if (threadIdx.x == 0 && blockIdx.x == 0)
        *flag = (ln1a[0] == 0) ? 1 : 0;   // 1 = inputs are fp32
}

// ---------------------------------------------------------------------------
// residual init/accumulate with positional embedding (raw inputs, flag dtype)
// ---------------------------------------------------------------------------
__global__ __launch_bounds__(256) void addpos_kernel(
    const void* __restrict__ xin, const void* __restrict__ pos, size_t posoff,
    float* __restrict__ xf, int init, const int* __restrict__ dflag)
{
    const bool f32 = (*dflag != 0);
    int i = blockIdx.x * 256 + threadIdx.x;
    if (i >= MT * DD) return;
    int td = i % TD;
    float p = ldin(pos, posoff + td, f32);
    if (init) xf[i] = ldin(xin, i, f32) + p;
    else      xf[i] += p;
}

// ---------------------------------------------------------------------------
// LayerNorm (torch: unbiased std (n-1), eps added to std)
// out: bf16 (ws) normally; final_o!=0 -> d_out in detected dtype
// ---------------------------------------------------------------------------
__global__ __launch_bounds__(256) void ln_kernel(
    const float* __restrict__ xf, const void* __restrict__ ga, size_t gaoff,
    const void* __restrict__ gb, size_t gboff,
    void* __restrict__ out, int final_o, const int* __restrict__ dflag)
{
    const bool f32 = (*dflag != 0);
    __shared__ float red[256];
    const int row = blockIdx.x;
    const int tid = threadIdx.x;
    const float* xr = xf + (size_t)row * DD;
    float x0 = xr[tid], x1 = xr[tid + 256];

    red[tid] = x0 + x1;
    __syncthreads();
    for (int o = 128; o > 0; o >>= 1) {
        if (tid < o) red[tid] += red[tid + o];
        __syncthreads();
    }
    float mean = red[0] * (1.0f / 512.0f);
    __syncthreads();
    float c0 = x0 - mean, c1 = x1 - mean;
    red[tid] = c0 * c0 + c1 * c1;
    __syncthreads();
    for (int o = 128; o > 0; o >>= 1) {
        if (tid < o) red[tid] += red[tid + o];
        __syncthreads();
    }
    float stdv = sqrtf(red[0] * (1.0f / 511.0f));
    float inv = 1.0f / (stdv + 1e-6f);
    float v0 = ldin(ga, gaoff + tid,       f32) * c0 * inv + ldin(gb, gboff + tid,       f32);
    float v1 = ldin(ga, gaoff + tid + 256, f32) * c1 * inv + ldin(gb, gboff + tid + 256, f32);
    if (final_o && f32) {
        float* orow = (float*)out + (size_t)row * DD;
        orow[tid] = v0; orow[tid + 256] = v1;
    } else {
        bf16* orow = (bf16*)out + (size_t)row * DD;
        orow[tid] = f2bf(v0); orow[tid + 256] = f2bf(v1);
    }
}

// ---------------------------------------------------------------------------
// Tiled GEMM: C[M,N] = A[M,K] @ W[N,K]^T + bias
// A: ws bf16 (a_ext=0) or raw input (a_ext=1, dtype per flag). W/bias: raw.
// mode 0: scatter bf16 to (chunkB,H,T,DK) | mode 1: relu bf16 MxN |
// mode 2: fp32 += into xf (stride DD)
// ---------------------------------------------------------------------------
__global__ __launch_bounds__(256) void gemm_kernel(
    const void* __restrict__ A, size_t aoff, int a_ext,
    const void* __restrict__ W, size_t woff,
    const void* __restrict__ bias, size_t boff, int has_bias,
    void* __restrict__ outp, int M, int N, int K, int mode,
    const int* __restrict__ dflag)
{
    const bool f32 = (*dflag != 0);
    const bool a32 = a_ext && f32;
    __shared__ float As[16][64];
    __shared__ float Bs[16][64];
    const int tid = threadIdx.x;
    const int m0 = blockIdx.y * 64, n0 = blockIdx.x * 64;
    const int tx = tid & 15, ty = tid >> 4;
    const int lr = tid >> 2;
    const int lk = (tid & 3) << 2;
    float acc[4][4] = {};

    const int mrow  = m0 + lr;
    const int mload = mrow < M ? mrow : (M - 1);
    const size_t abase = aoff + (size_t)mload * K + lk;
    const size_t wbase = woff + (size_t)(n0 + lr) * K + lk;

    for (int k0 = 0; k0 < K; k0 += 16) {
        if (a32) {
            float4 va = *(const float4*)((const float*)A + abase + k0);
            As[lk + 0][lr] = va.x; As[lk + 1][lr] = va.y;
            As[lk + 2][lr] = va.z; As[lk + 3][lr] = va.w;
        } else {
            unsigned long long ua = *(const unsigned long long*)((const bf16*)A + abase + k0);
            As[lk + 0][lr] = us2f((unsigned short)(ua));
            As[lk + 1][lr] = us2f((unsigned short)(ua >> 16));
            As[lk + 2][lr] = us2f((unsigned short)(ua >> 32));
            As[lk + 3][lr] = us2f((unsigned short)(ua >> 48));
        }
        if (f32) {
            float4 vb = *(const float4*)((const float*)W + wbase + k0);
            Bs[lk + 0][lr] = vb.x; Bs[lk + 1][lr] = vb.y;
            Bs[lk + 2][lr] = vb.z; Bs[lk + 3][lr] = vb.w;
        } else {
            unsigned long long ub = *(const unsigned long long*)((const bf16*)W + wbase + k0);
            Bs[lk + 0][lr] = us2f((unsigned short)(ub));
            Bs[lk + 1][lr] = us2f((unsigned short)(ub >> 16));
            Bs[lk + 2][lr] = us2f((unsigned short)(ub >> 32));
            Bs[lk + 3][lr] = us2f((unsigned short)(ub >> 48));
        }
        __syncthreads();
        #pragma unroll
        for (int kk = 0; kk < 16; ++kk) {
            float a[4], b[4];
            #pragma unroll
            for (int i = 0; i < 4; ++i) a[i] = As[kk][ty * 4 + i];
            #pragma unroll
            for (int j = 0; j < 4; ++j) b[j] = Bs[kk][tx * 4 + j];
            #pragma unroll
            for (int i = 0; i < 4; ++i)
                #pragma unroll
                for (int j = 0; j < 4; ++j)
                    acc[i][j] += a[i] * b[j];
        }
        __syncthreads();
    }

    #pragma unroll
    for (int i = 0; i < 4; ++i) {
        int m = m0 + ty * 4 + i;
        if (m >= M) continue;
        #pragma unroll
        for (int j = 0; j < 4; ++j) {
            int n = n0 + tx * 4 + j;
            float c = acc[i][j];
            if (has_bias) c += ldin(bias, boff + n, f32);
            if (mode == 0) {
                int b = m / TT, t = m - b * TT;
                int h = n >> 6, dk = n & 63;
                ((bf16*)outp)[((((size_t)b * HH + h) * TT + t) * DK) + dk] = f2bf(c);
            } else if (mode == 1) {
                ((bf16*)outp)[(size_t)m * N + n] = f2bf(fmaxf(c, 0.0f));
            } else {
                ((float*)outp)[(size_t)m * DD + n] += c;
            }
        }
    }
}

// ---------------------------------------------------------------------------
// Conv1d k=3 pad=1 over time + bias + residual add into xf (fp32)
// Hb: ws bf16, chunk-local (batch-aligned). W2/b2: raw inputs.
// ---------------------------------------------------------------------------
__global__ __launch_bounds__(256) void conv3_kernel(
    const bf16* __restrict__ Hb, const void* __restrict__ W2, size_t w2off,
    const void* __restrict__ b2, size_t b2off,
    float* __restrict__ xf, int M, const int* __restrict__ dflag)
{
    const bool f32 = (*dflag != 0);
    __shared__ float As[16][64];
    __shared__ float Bs[16][64];
    const int tid = threadIdx.x;
    const int m0 = blockIdx.y * 64, n0 = blockIdx.x * 64;
    const int tx = tid & 15, ty = tid >> 4;
    const int lr = tid >> 2;
    const int lk = (tid & 3) << 2;
    float acc[4][4] = {};

    const int mrow  = m0 + lr;
    const bool inr  = mrow < M;
    const int mload = inr ? mrow : (M - 1);
    const int trow  = mload % TT;

    for (int j = 0; j < 3; ++j) {
        int ts = trow + j - 1;
        bool valid = inr && (ts >= 0) && (ts < TT);
        const size_t wb = w2off + ((size_t)(n0 + lr) * FF + lk) * 3 + j;
        for (int k0 = 0; k0 < FF; k0 += 16) {
            if (valid) {
                const bf16* arow = Hb + (size_t)(mload + j - 1) * FF + lk + k0;
                unsigned long long ua = *(const unsigned long long*)arow;
                As[lk + 0][lr] = us2f((unsigned short)(ua));
                As[lk + 1][lr] = us2f((unsigned short)(ua >> 16));
                As[lk + 2][lr] = us2f((unsigned short)(ua >> 32));
                As[lk + 3][lr] = us2f((unsigned short)(ua >> 48));
            } else {
                As[lk + 0][lr] = 0.0f; As[lk + 1][lr] = 0.0f;
                As[lk + 2][lr] = 0.0f; As[lk + 3][lr] = 0.0f;
            }
            if (f32) {
                const float* wp = (const float*)W2 + wb + (size_t)k0 * 3;
                Bs[lk + 0][lr] = wp[0]; Bs[lk + 1][lr] = wp[3];
                Bs[lk + 2][lr] = wp[6]; Bs[lk + 3][lr] = wp[9];
            } else {
                const bf16* wp = (const bf16*)W2 + wb + (size_t)k0 * 3;
                Bs[lk + 0][lr] = bf2f(wp[0]); Bs[lk + 1][lr] = bf2f(wp[3]);
                Bs[lk + 2][lr] = bf2f(wp[6]); Bs[lk + 3][lr] = bf2f(wp[9]);
            }
            __syncthreads();
            #pragma unroll
            for (int kk = 0; kk < 16; ++kk) {
                float a[4], b[4];
                #pragma unroll
                for (int i = 0; i < 4; ++i) a[i] = As[kk][ty * 4 + i];
                #pragma unroll
                for (int jj = 0; jj < 4; ++jj) b[jj] = Bs[kk][tx * 4 + jj];
                #pragma unroll
                for (int i = 0; i < 4; ++i)
                    #pragma unroll
                    for (int jj = 0; jj < 4; ++jj)
                        acc[i][jj] += a[i] * b[jj];
            }
            __syncthreads();
        }
    }

    #pragma unroll
    for (int i = 0; i < 4; ++i) {
        int m = m0 + ty * 4 + i;
        if (m >= M) continue;
        #pragma unroll
        for (int j = 0; j < 4; ++j) {
            int n = n0 + tx * 4 + j;
            xf[(size_t)m * DD + n] += acc[i][j] + ldin(b2, b2off + n, f32);
        }
    }
}

// ---------------------------------------------------------------------------
// Fused relative attention, one block per (b_local, h, q).
// pos[k] = k<=q : (q[q]+v).P[k-q+T-1] | k==q+1 : 0 | k>q+1 : (q[q+1]+v).P[k-q-2]
// ---------------------------------------------------------------------------
__device__ __forceinline__ float dot64(const float* q, const bf16* row) {
    const unsigned long long* r = (const unsigned long long*)row;
    float acc = 0.0f;
    #pragma unroll
    for (int w = 0; w < 16; ++w) {
        unsigned long long u = r[w];
        acc += q[4 * w + 0] * us2f((unsigned short)(u));
        acc += q[4 * w + 1] * us2f((unsigned short)(u >> 16));
        acc += q[4 * w + 2] * us2f((unsigned short)(u >> 32));
        acc += q[4 * w + 3] * us2f((unsigned short)(u >> 48));
    }
    return acc;
}

__global__ __launch_bounds__(256) void attn_kernel(
    const bf16* __restrict__ Q, const bf16* __restrict__ Kb,
    const bf16* __restrict__ V, const bf16* __restrict__ P,
    const void* __restrict__ ubias, const void* __restrict__ vbias, size_t uvoff,
    bf16* __restrict__ ctx, const int* __restrict__ dflag)
{
    const bool f32 = (*dflag != 0);
    const int qi = blockIdx.x;
    const int h  = blockIdx.y;
    const int b  = blockIdx.z;
    const int tid = threadIdx.x;

    __shared__ float qu[DK], qv[DK], qv2[DK];
    __shared__ float s[TT];
    __shared__ float red[256];

    const size_t base = (((size_t)b * HH + h) * TT) * DK;

    if (tid < DK) {
        float uq = ldin(ubias, uvoff + h * DK + tid, f32);
        float vq = ldin(vbias, uvoff + h * DK + tid, f32);
        float qq = bf2f(Q[base + (size_t)qi * DK + tid]);
        qu[tid] = qq + uq;
        qv[tid] = qq + vq;
        float q2 = (qi + 1 < TT) ? bf2f(Q[base + (size_t)(qi + 1) * DK + tid]) : 0.0f;
        qv2[tid] = q2 + vq;
    }
    __syncthreads();

    const float scale = 0.04419417382415922f;  // 1/sqrt(512)
    for (int k = tid; k < TT; k += 256) {
        float c = dot64(qu, Kb + base + (size_t)k * DK);
        float p = 0.0f;
        if (k <= qi) {
            p = dot64(qv, P + base + (size_t)(k - qi + TT - 1) * DK);
        } else if (k > qi + 1) {
            p = dot64(qv2, P + base + (size_t)(k - qi - 2) * DK);
        }
        s[k] = (c + p) * scale;
    }
    __syncthreads();

    float lm = -1e30f;
    for (int k = tid; k < TT; k += 256) lm = fmaxf(lm, s[k]);
    red[tid] = lm;
    __syncthreads();
    for (int o = 128; o > 0; o >>= 1) {
        if (tid < o) red[tid] = fmaxf(red[tid], red[tid + o]);
        __syncthreads();
    }
    float mx = red[0];
    __syncthreads();
    float lsum = 0.0f;
    for (int k = tid; k < TT; k += 256) {
        float e = __expf(s[k] - mx);
        s[k] = e;
        lsum += e;
    }
    red[tid] = lsum;
    __syncthreads();
    for (int o = 128; o > 0; o >>= 1) {
        if (tid < o) red[tid] += red[tid + o];
        __syncthreads();
    }
    float inv = 1.0f / red[0];
    __syncthreads();

    const int d = tid & 63, kq = tid >> 6;
    float partial = 0.0f;
    for (int k = kq; k < TT; k += 4)
        partial += s[k] * bf2f(V[base + (size_t)k * DK + d]);
    red[tid] = partial;
    __syncthreads();
    if (tid < 64) {
        float r = (red[tid] + red[64 + tid] + red[128 + tid] + red[192 + tid]) * inv;
        ctx[((size_t)b * TT + qi) * DD + h * DK + tid] = f2bf(r);
    }
}

// ---------------------------------------------------------------------------
extern "C" void kernel_launch(void* const* d_in, const int* in_sizes, int n_in,
                              void* d_out, int out_size, void* d_ws, size_t ws_size,
                              hipStream_t stream)
{
    (void)in_sizes; (void)n_in; (void)out_size; (void)ws_size;
    const void* x    = d_in[0];
    const void* mask = d_in[1];
    const void* pos  = d_in[2];
    const void* Wq   = d_in[3];
    const void* bq   = d_in[4];
    const void* Wk   = d_in[5];
    const void* bk   = d_in[6];
    const void* Wv   = d_in[7];
    const void* bv   = d_in[8];
    const void* Wp   = d_in[9];
    const void* ub   = d_in[10];
    const void* vbi  = d_in[11];
    const void* Wo   = d_in[12];
    const void* bo   = d_in[13];
    const void* l1a  = d_in[14];
    const void* l1b  = d_in[15];
    const void* l2a  = d_in[16];
    const void* l2b  = d_in[17];
    const void* W1   = d_in[18];
    const void* b1   = d_in[19];
    const void* W2   = d_in[20];
    const void* b2   = d_in[21];
    const void* fa   = d_in[22];
    const void* fb   = d_in[23];

    // ws layout: flag(256B) | xf fp32 46MB | xn bf16 23MB | sc bf16 11.5MB
    char* w = (char*)d_ws;
    int*   dflag = (int*)w;
    float* xf = (float*)(w + 256);
    bf16*  xn = (bf16*)(w + 256 + (size_t)MT * DD * 4);
    bf16*  sc = (bf16*)(w + 256 + (size_t)MT * DD * 4 + (size_t)MT * DD * 2);
    bf16* qc = sc;
    bf16* kc = sc + (size_t)MA * DD;
    bf16* vc = sc + (size_t)2 * MA * DD;
    bf16* pc = sc + (size_t)3 * MA * DD;
    bf16* hb = sc;   // MF*FF == 4*MA*DD elements exactly

    dim3 blk(256);
    dim3 g_ep((MT * DD + 255) / 256);
    dim3 g_ln(MT);
    dim3 g_pA(8, (MA + 63) / 64);
    dim3 g_o(8, MT / 64);
    dim3 g_f1(16, (MF + 63) / 64);
    dim3 g_f2(8, (MF + 63) / 64);
    dim3 g_attn(TT, HH, CHA);

    detect_kernel<<<dim3(1), dim3(64), 0, stream>>>((const unsigned short*)l1a, dflag);

    for (int l = 0; l < LL; ++l) {
        addpos_kernel<<<g_ep, blk, 0, stream>>>(x, pos, (size_t)l * TD, xf, l == 0, dflag);
        ln_kernel<<<g_ln, blk, 0, stream>>>(xf, l1a, (size_t)l * DD, l1b, (size_t)l * DD, xn, 0, dflag);
        for (int c = 0; c < NCA; ++c) {
            bf16* xnc = xn + (size_t)c * MA * DD;
            gemm_kernel<<<g_pA, blk, 0, stream>>>(xnc, 0, 0, Wq, (size_t)l * DD * DD,
                                                  bq, (size_t)l * DD, 1, qc, MA, DD, DD, 0, dflag);
            gemm_kernel<<<g_pA, blk, 0, stream>>>(xnc, 0, 0, Wk, (size_t)l * DD * DD,
                                                  bk, (size_t)l * DD, 1, kc, MA, DD, DD, 0, dflag);
            gemm_kernel<<<g_pA, blk, 0, stream>>>(xnc, 0, 0, Wv, (size_t)l * DD * DD,
                                                  bv, (size_t)l * DD, 1, vc, MA, DD, DD, 0, dflag);
            gemm_kernel<<<g_pA, blk, 0, stream>>>(mask, (size_t)c * MA * DD, 1, Wp, (size_t)l * DD * DD,
                                                  nullptr, 0, 0, pc, MA, DD, DD, 0, dflag);
            attn_kernel<<<g_attn, blk, 0, stream>>>(qc, kc, vc, pc, ub, vbi,
                                                    (size_t)l * HH * DK, xnc, dflag);
        }
        gemm_kernel<<<g_o, blk, 0, stream>>>(xn, 0, 0, Wo, (size_t)l * DD * DD,
                                             bo, (size_t)l * DD, 1, xf, MT, DD, DD, 2, dflag);
        ln_kernel<<<g_ln, blk, 0, stream>>>(xf, l2a, (size_t)l * DD, l2b, (size_t)l * DD, xn, 0, dflag);
        for (int c = 0; c < NCF; ++c) {
            gemm_kernel<<<g_f1, blk, 0, stream>>>(xn + (size_t)c * MF * DD, 0, 0,
                                                  W1, (size_t)l * FF * DD, b1, (size_t)l * FF, 1,
                                                  hb, MF, FF, DD, 1, dflag);
            conv3_kernel<<<g_f2, blk, 0, stream>>>(hb, W2, (size_t)l * DD * FF * 3,
                                                   b2, (size_t)l * DD,
                                                   xf + (size_t)c * MF * DD, MF, dflag);
        }
    }
    ln_kernel<<<g_ln, blk, 0, stream>>>(xf, fa, 0, fb, 0, d_out, 1, dflag);
}

// Round 5
// 17241.336 us; speedup vs baseline: 3.6921x; 3.6921x over previous
//
#include <hip/hip_runtime.h>
#include <hip/hip_bf16.h>

typedef __hip_bfloat16 bf16;

constexpr int BB  = 64;
constexpr int TT  = 351;
constexpr int DD  = 512;
constexpr int HH  = 8;
constexpr int DK  = 64;
constexpr int FF  = 1024;
constexpr int LL  = 3;
constexpr int MT  = BB * TT;      // 22464
constexpr int TD  = TT * DD;

constexpr int CHA = 8;            // batches per attention chunk
constexpr int MA  = CHA * TT;     // 2808
constexpr int NCA = BB / CHA;     // 8
constexpr int CHF = 16;           // batches per FFN chunk
constexpr int MF  = CHF * TT;     // 5616
constexpr int NCF = BB / CHF;     // 4

constexpr int QT  = 32;                      // q rows per attn block
constexpr int NQT = (TT + QT - 1) / QT;      // 11

__device__ __forceinline__ float us2f(unsigned short u) {
    union { unsigned int i; float f; } c; c.i = ((unsigned int)u) << 16; return c.f;
}
__device__ __forceinline__ float bf2f(bf16 h) { return __bfloat162float(h); }
__device__ __forceinline__ bf16  f2bf(float f) { return __float2bfloat16(f); }
__device__ __forceinline__ float ldin(const void* p, size_t i, bool f32) {
    return f32 ? ((const float*)p)[i] : bf2f(((const bf16*)p)[i]);
}

// ---------------------------------------------------------------------------
// dtype detect: ln1_a is all-ones. fp32 1.0f low u16 = 0x0000; bf16 1.0=0x3F80
// ---------------------------------------------------------------------------
__global__ void detect_kernel(const unsigned short* ln1a, int* flag) {
    if (threadIdx.x == 0 && blockIdx.x == 0)
        *flag = (ln1a[0] == 0) ? 1 : 0;   // 1 = inputs are fp32
}

// ---------------------------------------------------------------------------
__global__ __launch_bounds__(256) void addpos_kernel(
    const void* __restrict__ xin, const void* __restrict__ pos, size_t posoff,
    float* __restrict__ xf, int init, const int* __restrict__ dflag)
{
    const bool f32 = (*dflag != 0);
    int i = blockIdx.x * 256 + threadIdx.x;
    if (i >= MT * DD) return;
    int td = i % TD;
    float p = ldin(pos, posoff + td, f32);
    if (init) xf[i] = ldin(xin, i, f32) + p;
    else      xf[i] += p;
}

// ---------------------------------------------------------------------------
// LayerNorm (torch: unbiased std (n-1), eps added to std)
// ---------------------------------------------------------------------------
__global__ __launch_bounds__(256) void ln_kernel(
    const float* __restrict__ xf, const void* __restrict__ ga, size_t gaoff,
    const void* __restrict__ gb, size_t gboff,
    void* __restrict__ out, int final_o, const int* __restrict__ dflag)
{
    const bool f32 = (*dflag != 0);
    __shared__ float red[256];
    const int row = blockIdx.x;
    const int tid = threadIdx.x;
    const float* xr = xf + (size_t)row * DD;
    float x0 = xr[tid], x1 = xr[tid + 256];

    red[tid] = x0 + x1;
    __syncthreads();
    for (int o = 128; o > 0; o >>= 1) {
        if (tid < o) red[tid] += red[tid + o];
        __syncthreads();
    }
    float mean = red[0] * (1.0f / 512.0f);
    __syncthreads();
    float c0 = x0 - mean, c1 = x1 - mean;
    red[tid] = c0 * c0 + c1 * c1;
    __syncthreads();
    for (int o = 128; o > 0; o >>= 1) {
        if (tid < o) red[tid] += red[tid + o];
        __syncthreads();
    }
    float stdv = sqrtf(red[0] * (1.0f / 511.0f));
    float inv = 1.0f / (stdv + 1e-6f);
    float v0 = ldin(ga, gaoff + tid,       f32) * c0 * inv + ldin(gb, gboff + tid,       f32);
    float v1 = ldin(ga, gaoff + tid + 256, f32) * c1 * inv + ldin(gb, gboff + tid + 256, f32);
    if (final_o && f32) {
        float* orow = (float*)out + (size_t)row * DD;
        orow[tid] = v0; orow[tid + 256] = v1;
    } else {
        bf16* orow = (bf16*)out + (size_t)row * DD;
        orow[tid] = f2bf(v0); orow[tid + 256] = f2bf(v1);
    }
}

// ---------------------------------------------------------------------------
// Tiled GEMM: C[M,N] = A[M,K] @ W[N,K]^T + bias
// ---------------------------------------------------------------------------
__global__ __launch_bounds__(256) void gemm_kernel(
    const void* __restrict__ A, size_t aoff, int a_ext,
    const void* __restrict__ W, size_t woff,
    const void* __restrict__ bias, size_t boff, int has_bias,
    void* __restrict__ outp, int M, int N, int K, int mode,
    const int* __restrict__ dflag)
{
    const bool f32 = (*dflag != 0);
    const bool a32 = a_ext && f32;
    __shared__ float As[16][64];
    __shared__ float Bs[16][64];
    const int tid = threadIdx.x;
    const int m0 = blockIdx.y * 64, n0 = blockIdx.x * 64;
    const int tx = tid & 15, ty = tid >> 4;
    const int lr = tid >> 2;
    const int lk = (tid & 3) << 2;
    float acc[4][4] = {};

    const int mrow  = m0 + lr;
    const int mload = mrow < M ? mrow : (M - 1);
    const size_t abase = aoff + (size_t)mload * K + lk;
    const size_t wbase = woff + (size_t)(n0 + lr) * K + lk;

    for (int k0 = 0; k0 < K; k0 += 16) {
        if (a32) {
            float4 va = *(const float4*)((const float*)A + abase + k0);
            As[lk + 0][lr] = va.x; As[lk + 1][lr] = va.y;
            As[lk + 2][lr] = va.z; As[lk + 3][lr] = va.w;
        } else {
            unsigned long long ua = *(const unsigned long long*)((const bf16*)A + abase + k0);
            As[lk + 0][lr] = us2f((unsigned short)(ua));
            As[lk + 1][lr] = us2f((unsigned short)(ua >> 16));
            As[lk + 2][lr] = us2f((unsigned short)(ua >> 32));
            As[lk + 3][lr] = us2f((unsigned short)(ua >> 48));
        }
        if (f32) {
            float4 vb = *(const float4*)((const float*)W + wbase + k0);
            Bs[lk + 0][lr] = vb.x; Bs[lk + 1][lr] = vb.y;
            Bs[lk + 2][lr] = vb.z; Bs[lk + 3][lr] = vb.w;
        } else {
            unsigned long long ub = *(const unsigned long long*)((const bf16*)W + wbase + k0);
            Bs[lk + 0][lr] = us2f((unsigned short)(ub));
            Bs[lk + 1][lr] = us2f((unsigned short)(ub >> 16));
            Bs[lk + 2][lr] = us2f((unsigned short)(ub >> 32));
            Bs[lk + 3][lr] = us2f((unsigned short)(ub >> 48));
        }
        __syncthreads();
        #pragma unroll
        for (int kk = 0; kk < 16; ++kk) {
            float a[4], b[4];
            #pragma unroll
            for (int i = 0; i < 4; ++i) a[i] = As[kk][ty * 4 + i];
            #pragma unroll
            for (int j = 0; j < 4; ++j) b[j] = Bs[kk][tx * 4 + j];
            #pragma unroll
            for (int i = 0; i < 4; ++i)
                #pragma unroll
                for (int j = 0; j < 4; ++j)
                    acc[i][j] += a[i] * b[j];
        }
        __syncthreads();
    }

    #pragma unroll
    for (int i = 0; i < 4; ++i) {
        int m = m0 + ty * 4 + i;
        if (m >= M) continue;
        #pragma unroll
        for (int j = 0; j < 4; ++j) {
            int n = n0 + tx * 4 + j;
            float c = acc[i][j];
            if (has_bias) c += ldin(bias, boff + n, f32);
            if (mode == 0) {
                int b = m / TT, t = m - b * TT;
                int h = n >> 6, dk = n & 63;
                ((bf16*)outp)[((((size_t)b * HH + h) * TT + t) * DK) + dk] = f2bf(c);
            } else if (mode == 1) {
                ((bf16*)outp)[(size_t)m * N + n] = f2bf(fmaxf(c, 0.0f));
            } else {
                ((float*)outp)[(size_t)m * DD + n] += c;
            }
        }
    }
}

// ---------------------------------------------------------------------------
// Conv1d k=3 pad=1 over time + bias + residual add into xf (fp32)
// ---------------------------------------------------------------------------
__global__ __launch_bounds__(256) void conv3_kernel(
    const bf16* __restrict__ Hb, const void* __restrict__ W2, size_t w2off,
    const void* __restrict__ b2, size_t b2off,
    float* __restrict__ xf, int M, const int* __restrict__ dflag)
{
    const bool f32 = (*dflag != 0);
    __shared__ float As[16][64];
    __shared__ float Bs[16][64];
    const int tid = threadIdx.x;
    const int m0 = blockIdx.y * 64, n0 = blockIdx.x * 64;
    const int tx = tid & 15, ty = tid >> 4;
    const int lr = tid >> 2;
    const int lk = (tid & 3) << 2;
    float acc[4][4] = {};

    const int mrow  = m0 + lr;
    const bool inr  = mrow < M;
    const int mload = inr ? mrow : (M - 1);
    const int trow  = mload % TT;

    for (int j = 0; j < 3; ++j) {
        int ts = trow + j - 1;
        bool valid = inr && (ts >= 0) && (ts < TT);
        const size_t wb = w2off + ((size_t)(n0 + lr) * FF + lk) * 3 + j;
        for (int k0 = 0; k0 < FF; k0 += 16) {
            if (valid) {
                const bf16* arow = Hb + (size_t)(mload + j - 1) * FF + lk + k0;
                unsigned long long ua = *(const unsigned long long*)arow;
                As[lk + 0][lr] = us2f((unsigned short)(ua));
                As[lk + 1][lr] = us2f((unsigned short)(ua >> 16));
                As[lk + 2][lr] = us2f((unsigned short)(ua >> 32));
                As[lk + 3][lr] = us2f((unsigned short)(ua >> 48));
            } else {
                As[lk + 0][lr] = 0.0f; As[lk + 1][lr] = 0.0f;
                As[lk + 2][lr] = 0.0f; As[lk + 3][lr] = 0.0f;
            }
            if (f32) {
                const float* wp = (const float*)W2 + wb + (size_t)k0 * 3;
                Bs[lk + 0][lr] = wp[0]; Bs[lk + 1][lr] = wp[3];
                Bs[lk + 2][lr] = wp[6]; Bs[lk + 3][lr] = wp[9];
            } else {
                const bf16* wp = (const bf16*)W2 + wb + (size_t)k0 * 3;
                Bs[lk + 0][lr] = bf2f(wp[0]); Bs[lk + 1][lr] = bf2f(wp[3]);
                Bs[lk + 2][lr] = bf2f(wp[6]); Bs[lk + 3][lr] = bf2f(wp[9]);
            }
            __syncthreads();
            #pragma unroll
            for (int kk = 0; kk < 16; ++kk) {
                float a[4], b[4];
                #pragma unroll
                for (int i = 0; i < 4; ++i) a[i] = As[kk][ty * 4 + i];
                #pragma unroll
                for (int jj = 0; jj < 4; ++jj) b[jj] = Bs[kk][tx * 4 + jj];
                #pragma unroll
                for (int i = 0; i < 4; ++i)
                    #pragma unroll
                    for (int jj = 0; jj < 4; ++jj)
                        acc[i][jj] += a[i] * b[jj];
            }
            __syncthreads();
        }
    }

    #pragma unroll
    for (int i = 0; i < 4; ++i) {
        int m = m0 + ty * 4 + i;
        if (m >= M) continue;
        #pragma unroll
        for (int j = 0; j < 4; ++j) {
            int n = n0 + tx * 4 + j;
            xf[(size_t)m * DD + n] += acc[i][j] + ldin(b2, b2off + n, f32);
        }
    }
}

// ---------------------------------------------------------------------------
// Fused relative attention v2: one block per (b_local, h, 32-row q-tile).
// PS[q][j] = (Q[q0+q]+v).P[j]  (33 rows: q0..q0+32)
// S[q][k]  = ((Q[q0+q]+u).K[k] + relshift(PS)) / sqrt(D); softmax; PV.
// relshift: k<=qr -> PS[q][k-qr+T-1] ; k==qr+1 -> 0 ; k>qr+1 -> PS[q+1][k-qr-2]
// ---------------------------------------------------------------------------
__global__ __launch_bounds__(256) void attn_kernel(
    const bf16* __restrict__ Q, const bf16* __restrict__ Kb,
    const bf16* __restrict__ V, const bf16* __restrict__ P,
    const void* __restrict__ ubias, const void* __restrict__ vbias, size_t uvoff,
    bf16* __restrict__ ctx, const int* __restrict__ dflag)
{
    const bool f32 = (*dflag != 0);
    const int qt = blockIdx.x;
    const int h  = blockIdx.y;
    const int b  = blockIdx.z;
    const int q0 = qt * QT;
    const int tid = threadIdx.x;

    __shared__ float S[QT][353];
    __shared__ float PS[QT + 1][353];
    __shared__ float qu[QT][DK];
    __shared__ float qv[QT + 1][DK];
    __shared__ float rowinv[QT];

    const size_t base = (((size_t)b * HH + h) * TT) * DK;
    const float scale = 0.04419417382415922f;  // 1/sqrt(512)

    // Phase A: stage Q+u (32 rows) and Q+v (33 rows) in LDS
    for (int i = tid; i < (QT + 1) * DK; i += 256) {
        int q = i >> 6, d = i & 63;
        int qrow = q0 + q;
        float qq = (qrow < TT) ? bf2f(Q[base + (size_t)qrow * DK + d]) : 0.0f;
        qv[q][d] = qq + ldin(vbias, uvoff + h * DK + d, f32);
        if (q < QT) qu[q][d] = qq + ldin(ubias, uvoff + h * DK + d, f32);
    }
    __syncthreads();

    // Phase B: PS strip (33 x 351); one thread per j-column
    for (int j = tid; j < TT; j += 256) {
        unsigned long long pr[16];
        const unsigned long long* prow = (const unsigned long long*)(P + base + (size_t)j * DK);
        #pragma unroll
        for (int w = 0; w < 16; ++w) pr[w] = prow[w];
        for (int q = 0; q <= QT; ++q) {
            const float* qr = qv[q];
            float acc = 0.0f;
            #pragma unroll
            for (int w = 0; w < 16; ++w) {
                unsigned long long u = pr[w];
                acc += qr[4 * w + 0] * us2f((unsigned short)(u));
                acc += qr[4 * w + 1] * us2f((unsigned short)(u >> 16));
                acc += qr[4 * w + 2] * us2f((unsigned short)(u >> 32));
                acc += qr[4 * w + 3] * us2f((unsigned short)(u >> 48));
            }
            PS[q][j] = acc;
        }
    }
    __syncthreads();

    // Phase C: content + rel_shift combine -> S
    for (int k = tid; k < TT; k += 256) {
        unsigned long long kr[16];
        const unsigned long long* krow = (const unsigned long long*)(Kb + base + (size_t)k * DK);
        #pragma unroll
        for (int w = 0; w < 16; ++w) kr[w] = krow[w];
        for (int q = 0; q < QT; ++q) {
            const float* qr = qu[q];
            float acc = 0.0f;
            #pragma unroll
            for (int w = 0; w < 16; ++w) {
                unsigned long long u = kr[w];
                acc += qr[4 * w + 0] * us2f((unsigned short)(u));
                acc += qr[4 * w + 1] * us2f((unsigned short)(u >> 16));
                acc += qr[4 * w + 2] * us2f((unsigned short)(u >> 32));
                acc += qr[4 * w + 3] * us2f((unsigned short)(u >> 48));
            }
            int qr_ = q0 + q;
            float ps;
            if (k <= qr_)            ps = PS[q][k - qr_ + TT - 1];
            else if (k == qr_ + 1)   ps = 0.0f;
            else                     ps = PS[q + 1][k - qr_ - 2];
            S[q][k] = (acc + ps) * scale;
        }
    }
    __syncthreads();

    // Phase D: softmax per row; 8 lanes per row
    {
        const int q = tid >> 3, k0 = tid & 7;
        float m = -1e30f;
        for (int k = k0; k < TT; k += 8) m = fmaxf(m, S[q][k]);
        #pragma unroll
        for (int msk = 1; msk < 8; msk <<= 1) m = fmaxf(m, __shfl_xor(m, msk));
        float sum = 0.0f;
        for (int k = k0; k < TT; k += 8) {
            float e = __expf(S[q][k] - m);
            S[q][k] = e;
            sum += e;
        }
        #pragma unroll
        for (int msk = 1; msk < 8; msk <<= 1) sum += __shfl_xor(sum, msk);
        if (k0 == 0) rowinv[q] = 1.0f / sum;
    }
    __syncthreads();

    // Phase E: PV; wave = 8 q-rows, lane d = tid&63
    {
        const int d = tid & 63;
        const int strip = tid >> 6;   // 0..3
        float acc[8] = {};
        for (int k = 0; k < TT; ++k) {
            float v = bf2f(V[base + (size_t)k * DK + d]);
            #pragma unroll
            for (int qq = 0; qq < 8; ++qq)
                acc[qq] += S[strip * 8 + qq][k] * v;
        }
        #pragma unroll
        for (int qq = 0; qq < 8; ++qq) {
            int q = strip * 8 + qq, qrow = q0 + q;
            if (qrow < TT)
                ctx[((size_t)b * TT + qrow) * DD + h * DK + d] = f2bf(acc[qq] * rowinv[q]);
        }
    }
}

// ---------------------------------------------------------------------------
extern "C" void kernel_launch(void* const* d_in, const int* in_sizes, int n_in,
                              void* d_out, int out_size, void* d_ws, size_t ws_size,
                              hipStream_t stream)
{
    (void)in_sizes; (void)n_in; (void)out_size; (void)ws_size;
    const void* x    = d_in[0];
    const void* mask = d_in[1];
    const void* pos  = d_in[2];
    const void* Wq   = d_in[3];
    const void* bq   = d_in[4];
    const void* Wk   = d_in[5];
    const void* bk   = d_in[6];
    const void* Wv   = d_in[7];
    const void* bv   = d_in[8];
    const void* Wp   = d_in[9];
    const void* ub   = d_in[10];
    const void* vbi  = d_in[11];
    const void* Wo   = d_in[12];
    const void* bo   = d_in[13];
    const void* l1a  = d_in[14];
    const void* l1b  = d_in[15];
    const void* l2a  = d_in[16];
    const void* l2b  = d_in[17];
    const void* W1   = d_in[18];
    const void* b1   = d_in[19];
    const void* W2   = d_in[20];
    const void* b2   = d_in[21];
    const void* fa   = d_in[22];
    const void* fb   = d_in[23];

    // ws layout: flag(256B) | xf fp32 46MB | xn bf16 23MB | sc bf16 11.5MB
    char* w = (char*)d_ws;
    int*   dflag = (int*)w;
    float* xf = (float*)(w + 256);
    bf16*  xn = (bf16*)(w + 256 + (size_t)MT * DD * 4);
    bf16*  sc = (bf16*)(w + 256 + (size_t)MT * DD * 4 + (size_t)MT * DD * 2);
    bf16* qc = sc;
    bf16* kc = sc + (size_t)MA * DD;
    bf16* vc = sc + (size_t)2 * MA * DD;
    bf16* pc = sc + (size_t)3 * MA * DD;
    bf16* hb = sc;   // MF*FF == 4*MA*DD elements exactly

    dim3 blk(256);
    dim3 g_ep((MT * DD + 255) / 256);
    dim3 g_ln(MT);
    dim3 g_pA(8, (MA + 63) / 64);
    dim3 g_o(8, MT / 64);
    dim3 g_f1(16, (MF + 63) / 64);
    dim3 g_f2(8, (MF + 63) / 64);
    dim3 g_attn(NQT, HH, CHA);

    detect_kernel<<<dim3(1), dim3(64), 0, stream>>>((const unsigned short*)l1a, dflag);

    for (int l = 0; l < LL; ++l) {
        addpos_kernel<<<g_ep, blk, 0, stream>>>(x, pos, (size_t)l * TD, xf, l == 0, dflag);
        ln_kernel<<<g_ln, blk, 0, stream>>>(xf, l1a, (size_t)l * DD, l1b, (size_t)l * DD, xn, 0, dflag);
        for (int c = 0; c < NCA; ++c) {
            bf16* xnc = xn + (size_t)c * MA * DD;
            gemm_kernel<<<g_pA, blk, 0, stream>>>(xnc, 0, 0, Wq, (size_t)l * DD * DD,
                                                  bq, (size_t)l * DD, 1, qc, MA, DD, DD, 0, dflag);
            gemm_kernel<<<g_pA, blk, 0, stream>>>(xnc, 0, 0, Wk, (size_t)l * DD * DD,
                                                  bk, (size_t)l * DD, 1, kc, MA, DD, DD, 0, dflag);
            gemm_kernel<<<g_pA, blk, 0, stream>>>(xnc, 0, 0, Wv, (size_t)l * DD * DD,
                                                  bv, (size_t)l * DD, 1, vc, MA, DD, DD, 0, dflag);
            gemm_kernel<<<g_pA, blk, 0, stream>>>(mask, (size_t)c * MA * DD, 1, Wp, (size_t)l * DD * DD,
                                                  nullptr, 0, 0, pc, MA, DD, DD, 0, dflag);
            attn_kernel<<<g_attn, blk, 0, stream>>>(qc, kc, vc, pc, ub, vbi,
                                                    (size_t)l * HH * DK, xnc, dflag);
        }
        gemm_kernel<<<g_o, blk, 0, stream>>>(xn, 0, 0, Wo, (size_t)l * DD * DD,
                                             bo, (size_t)l * DD, 1, xf, MT, DD, DD, 2, dflag);
        ln_kernel<<<g_ln, blk, 0, stream>>>(xf, l2a, (size_t)l * DD, l2b, (size_t)l * DD, xn, 0, dflag);
        for (int c = 0; c < NCF; ++c) {
            gemm_kernel<<<g_f1, blk, 0, stream>>>(xn + (size_t)c * MF * DD, 0, 0,
                                                  W1, (size_t)l * FF * DD, b1, (size_t)l * FF, 1,
                                                  hb, MF, FF, DD, 1, dflag);
            conv3_kernel<<<g_f2, blk, 0, stream>>>(hb, W2, (size_t)l * DD * FF * 3,
                                                   b2, (size_t)l * DD,
                                                   xf + (size_t)c * MF * DD, MF, dflag);
        }
    }
    ln_kernel<<<g_ln, blk, 0, stream>>>(xf, fa, 0, fb, 0, d_out, 1, dflag);
}

// Round 6
// 8051.988 us; speedup vs baseline: 7.9056x; 2.1413x over previous
//
#include <hip/hip_runtime.h>
#include <hip/hip_bf16.h>

typedef __hip_bfloat16 bf16;
typedef __attribute__((ext_vector_type(8))) short short8;
typedef __attribute__((ext_vector_type(4))) float f32x4;

constexpr int BB  = 64;
constexpr int TT  = 351;
constexpr int DD  = 512;
constexpr int HH  = 8;
constexpr int DK  = 64;
constexpr int FF  = 1024;
constexpr int LL  = 3;
constexpr int MT  = BB * TT;      // 22464
constexpr int TD  = TT * DD;

constexpr int QT  = 32;                      // q rows per attn block
constexpr int NQT = (TT + QT - 1) / QT;      // 11

// converted-weight layout in d_out (elements, bf16)
constexpr size_t LW      = 3407872;          // per-layer stride
constexpr size_t OFF_QKV = 0;                // [1536][512]
constexpr size_t OFF_P   = 786432;           // [512][512]
constexpr size_t OFF_O   = 1048576;          // [512][512]
constexpr size_t OFF_W1  = 1310720;          // [1024][512]
constexpr size_t OFF_W2  = 1835008;          // [3][512][1024]

__device__ __forceinline__ float us2f(unsigned short u) {
    union { unsigned int i; float f; } c; c.i = ((unsigned int)u) << 16; return c.f;
}
__device__ __forceinline__ float bf2f(bf16 h) { return __bfloat162float(h); }
__device__ __forceinline__ bf16  f2bf(float f) { return __float2bfloat16(f); }
__device__ __forceinline__ float ldin(const void* p, size_t i, bool f32) {
    return f32 ? ((const float*)p)[i] : bf2f(((const bf16*)p)[i]);
}
__device__ __forceinline__ unsigned short f2us(float f) {
    bf16 h = f2bf(f); return *reinterpret_cast<unsigned short*>(&h);
}

// ---------------------------------------------------------------------------
// dtype detect: ln1_a is all-ones. fp32 1.0f low u16 = 0x0000; bf16 1.0=0x3F80
// ---------------------------------------------------------------------------
__global__ void detect_kernel(const unsigned short* ln1a, int* flag) {
    if (threadIdx.x == 0 && blockIdx.x == 0)
        *flag = (ln1a[0] == 0) ? 1 : 0;   // 1 = inputs are fp32
}

// ---------------------------------------------------------------------------
// weight conversion into wbuf (d_out scratch). mode 0: plain copy.
// mode 1: W2 transpose  dst[j][n][f] = src[n][f][j]
// ---------------------------------------------------------------------------
__global__ __launch_bounds__(256) void cvt_kernel(
    const void* __restrict__ src, size_t S, size_t slstride,
    bf16* __restrict__ dst, size_t doff, int nl, int mode,
    const int* __restrict__ dflag)
{
    const bool f32 = (*dflag != 0);
    size_t i = (size_t)blockIdx.x * 256 + threadIdx.x;
    size_t total = (size_t)nl * S;
    if (i >= total) return;
    size_t l = i / S, e = i - l * S;
    size_t se;
    if (mode == 1) {
        size_t j = e >> 19;
        size_t nf = e & ((1u << 19) - 1);
        size_t n = nf >> 10, f = nf & 1023;
        se = n * 3072 + f * 3 + j;
    } else se = e;
    dst[doff + l * LW + e] = f2bf(ldin(src, l * slstride + se, f32));
}

// ---------------------------------------------------------------------------
__global__ __launch_bounds__(256) void addpos_kernel(
    const void* __restrict__ xin, const void* __restrict__ pos, size_t posoff,
    float* __restrict__ xf, int init, const int* __restrict__ dflag)
{
    const bool f32 = (*dflag != 0);
    int i = blockIdx.x * 256 + threadIdx.x;
    if (i >= MT * DD) return;
    int td = i % TD;
    float p = ldin(pos, posoff + td, f32);
    if (init) xf[i] = ldin(xin, i, f32) + p;
    else      xf[i] += p;
}

// ---------------------------------------------------------------------------
// LayerNorm (torch: unbiased std (n-1), eps added to std)
// ---------------------------------------------------------------------------
__global__ __launch_bounds__(256) void ln_kernel(
    const float* __restrict__ xf, const void* __restrict__ ga, size_t gaoff,
    const void* __restrict__ gb, size_t gboff,
    void* __restrict__ out, int final_o, const int* __restrict__ dflag)
{
    const bool f32 = (*dflag != 0);
    __shared__ float red[256];
    const int row = blockIdx.x;
    const int tid = threadIdx.x;
    const float* xr = xf + (size_t)row * DD;
    float x0 = xr[tid], x1 = xr[tid + 256];

    red[tid] = x0 + x1;
    __syncthreads();
    for (int o = 128; o > 0; o >>= 1) {
        if (tid < o) red[tid] += red[tid + o];
        __syncthreads();
    }
    float mean = red[0] * (1.0f / 512.0f);
    __syncthreads();
    float c0 = x0 - mean, c1 = x1 - mean;
    red[tid] = c0 * c0 + c1 * c1;
    __syncthreads();
    for (int o = 128; o > 0; o >>= 1) {
        if (tid < o) red[tid] += red[tid + o];
        __syncthreads();
    }
    float stdv = sqrtf(red[0] * (1.0f / 511.0f));
    float inv = 1.0f / (stdv + 1e-6f);
    float v0 = ldin(ga, gaoff + tid,       f32) * c0 * inv + ldin(gb, gboff + tid,       f32);
    float v1 = ldin(ga, gaoff + tid + 256, f32) * c1 * inv + ldin(gb, gboff + tid + 256, f32);
    if (final_o && f32) {
        float* orow = (float*)out + (size_t)row * DD;
        orow[tid] = v0; orow[tid + 256] = v1;
    } else {
        bf16* orow = (bf16*)out + (size_t)row * DD;
        orow[tid] = f2bf(v0); orow[tid + 256] = f2bf(v1);
    }
}

// ---------------------------------------------------------------------------
// MFMA GEMM: C[M,N] = A[M,K] @ W[N,K]^T (+bias). 128x128 tile, 4 waves.
// A: bf16 ws (a_ext=0) or raw input (a_ext=1, dtype per flag). W: bf16.
// mode 0: scatter bf16 (chunkB,H,T,DK); which=n>>9 picks q/k/v buffer (+chN)
// mode 1: relu -> bf16 [M][N]
// mode 2: fp32 += into xf [M][DD]
// ---------------------------------------------------------------------------
__global__ __launch_bounds__(256) void mgemm_kernel(
    const void* __restrict__ A, size_t aoff, int a_ext,
    const bf16* __restrict__ W,
    const void* __restrict__ b0, const void* __restrict__ b1p,
    const void* __restrict__ b2p, size_t boff,
    void* __restrict__ outp, int M, int N, int K, int mode, int chN,
    const int* __restrict__ dflag)
{
    const bool f32 = (*dflag != 0);
    const bool a32 = a_ext && f32;
    __shared__ unsigned short As[128][40];
    __shared__ unsigned short Bs[128][40];
    const int tid = threadIdx.x;
    const int n0 = blockIdx.x * 128, m0 = blockIdx.y * 128;

    const int lane = tid & 63, wv = tid >> 6;
    const int wm = wv >> 1, wn = wv & 1;
    const int q = lane >> 4, lm = lane & 15;

    f32x4 acc[4][4] = {};

    for (int k0 = 0; k0 < K; k0 += 32) {
        #pragma unroll
        for (int part = 0; part < 2; ++part) {
            int idx = part * 256 + tid;
            int row = idx >> 2;
            int seg = (idx & 3) * 8;
            int grow = m0 + row; if (grow >= M) grow = M - 1;
            if (a32) {
                const float* ap = (const float*)A + aoff + (size_t)grow * K + k0 + seg;
                union { unsigned short us[8]; int4 v; } t;
                #pragma unroll
                for (int e = 0; e < 8; ++e) t.us[e] = f2us(ap[e]);
                *(int4*)&As[row][seg] = t.v;
            } else {
                *(int4*)&As[row][seg] =
                    *(const int4*)((const bf16*)A + aoff + (size_t)grow * K + k0 + seg);
            }
            *(int4*)&Bs[row][seg] =
                *(const int4*)(W + (size_t)(n0 + row) * K + k0 + seg);
        }
        __syncthreads();
        short8 af[4], bfv[4];
        #pragma unroll
        for (int i = 0; i < 4; ++i) af[i]  = *(const short8*)&As[wm * 64 + i * 16 + lm][q * 8];
        #pragma unroll
        for (int j = 0; j < 4; ++j) bfv[j] = *(const short8*)&Bs[wn * 64 + j * 16 + lm][q * 8];
        #pragma unroll
        for (int i = 0; i < 4; ++i)
            #pragma unroll
            for (int j = 0; j < 4; ++j)
                acc[i][j] = __builtin_amdgcn_mfma_f32_16x16x32_bf16(af[i], bfv[j], acc[i][j], 0, 0, 0);
        __syncthreads();
    }

    #pragma unroll
    for (int i = 0; i < 4; ++i) {
        #pragma unroll
        for (int j = 0; j < 4; ++j) {
            #pragma unroll
            for (int r = 0; r < 4; ++r) {
                int m = m0 + wm * 64 + i * 16 + q * 4 + r;
                if (m >= M) continue;
                int n = n0 + wn * 64 + j * 16 + lm;
                float c = acc[i][j][r];
                if (mode == 0) {
                    int which = n >> 9;
                    int nn = n & 511;
                    const void* bp = which == 0 ? b0 : (which == 1 ? b1p : b2p);
                    if (bp) c += ldin(bp, boff + nn, f32);
                    int b = m / TT, t = m - b * TT;
                    int h = nn >> 6, dk = nn & 63;
                    ((bf16*)outp)[(size_t)which * chN +
                                  ((((size_t)b * HH + h) * TT + t) * DK) + dk] = f2bf(c);
                } else if (mode == 1) {
                    if (b0) c += ldin(b0, boff + n, f32);
                    ((bf16*)outp)[(size_t)m * N + n] = f2bf(fmaxf(c, 0.0f));
                } else {
                    if (b0) c += ldin(b0, boff + n, f32);
                    ((float*)outp)[(size_t)m * DD + n] += c;
                }
            }
        }
    }
}

// ---------------------------------------------------------------------------
// MFMA conv1d k=3 pad=1: y[m,n] = sum_j sum_f w2r[j][n][f] * h[m+j-1,f]
// += into xf (fp32) with bias. Hb chunk-local (batch-aligned).
// ---------------------------------------------------------------------------
__global__ __launch_bounds__(256) void mconv_kernel(
    const bf16* __restrict__ Hb, const bf16* __restrict__ Wc,
    const void* __restrict__ bias, size_t boff,
    float* __restrict__ xf, int M, const int* __restrict__ dflag)
{
    const bool f32 = (*dflag != 0);
    __shared__ unsigned short As[128][40];
    __shared__ unsigned short Bs[128][40];
    const int tid = threadIdx.x;
    const int n0 = blockIdx.x * 128, m0 = blockIdx.y * 128;

    const int lane = tid & 63, wv = tid >> 6;
    const int wm = wv >> 1, wn = wv & 1;
    const int q = lane >> 4, lm = lane & 15;

    // per-part staging geometry (constant across k)
    int rowP[2], segP[2], mloadP[2], trowP[2];
    bool inrP[2];
    #pragma unroll
    for (int part = 0; part < 2; ++part) {
        int idx = part * 256 + tid;
        rowP[part] = idx >> 2;
        segP[part] = (idx & 3) * 8;
        int mrow = m0 + rowP[part];
        inrP[part] = mrow < M;
        int mload = inrP[part] ? mrow : (M - 1);
        mloadP[part] = mload;
        trowP[part] = mload % TT;
    }

    f32x4 acc[4][4] = {};

    for (int j = 0; j < 3; ++j) {
        for (int k0 = 0; k0 < FF; k0 += 32) {
            #pragma unroll
            for (int part = 0; part < 2; ++part) {
                int row = rowP[part], seg = segP[part];
                int ts = trowP[part] + j - 1;
                bool valid = inrP[part] && ts >= 0 && ts < TT;
                if (valid) {
                    *(int4*)&As[row][seg] =
                        *(const int4*)(Hb + (size_t)(mloadP[part] + j - 1) * FF + k0 + seg);
                } else {
                    int4 z = {0, 0, 0, 0};
                    *(int4*)&As[row][seg] = z;
                }
                *(int4*)&Bs[row][seg] =
                    *(const int4*)(Wc + (size_t)j * 524288 + (size_t)(n0 + row) * FF + k0 + seg);
            }
            __syncthreads();
            short8 af[4], bfv[4];
            #pragma unroll
            for (int i = 0; i < 4; ++i) af[i]  = *(const short8*)&As[wm * 64 + i * 16 + lm][q * 8];
            #pragma unroll
            for (int jj = 0; jj < 4; ++jj) bfv[jj] = *(const short8*)&Bs[wn * 64 + jj * 16 + lm][q * 8];
            #pragma unroll
            for (int i = 0; i < 4; ++i)
                #pragma unroll
                for (int jj = 0; jj < 4; ++jj)
                    acc[i][jj] = __builtin_amdgcn_mfma_f32_16x16x32_bf16(af[i], bfv[jj], acc[i][jj], 0, 0, 0);
            __syncthreads();
        }
    }

    #pragma unroll
    for (int i = 0; i < 4; ++i) {
        #pragma unroll
        for (int jj = 0; jj < 4; ++jj) {
            #pragma unroll
            for (int r = 0; r < 4; ++r) {
                int m = m0 + wm * 64 + i * 16 + q * 4 + r;
                if (m >= M) continue;
                int n = n0 + wn * 64 + jj * 16 + lm;
                xf[(size_t)m * DD + n] += acc[i][jj][r] + ldin(bias, boff + n, f32);
            }
        }
    }
}

// ---------------------------------------------------------------------------
// Fused relative attention (proven v2): one block per (b_local, h, q-tile).
// ---------------------------------------------------------------------------
__global__ __launch_bounds__(256) void attn_kernel(
    const bf16* __restrict__ Q, const bf16* __restrict__ Kb,
    const bf16* __restrict__ V, const bf16* __restrict__ P,
    const void* __restrict__ ubias, const void* __restrict__ vbias, size_t uvoff,
    bf16* __restrict__ ctx, const int* __restrict__ dflag)
{
    const bool f32 = (*dflag != 0);
    const int qt = blockIdx.x;
    const int h  = blockIdx.y;
    const int b  = blockIdx.z;
    const int q0 = qt * QT;
    const int tid = threadIdx.x;

    __shared__ float S[QT][353];
    __shared__ float PS[QT + 1][353];
    __shared__ float qu[QT][DK];
    __shared__ float qv[QT + 1][DK];
    __shared__ float rowinv[QT];

    const size_t base = (((size_t)b * HH + h) * TT) * DK;
    const float scale = 0.04419417382415922f;  // 1/sqrt(512)

    for (int i = tid; i < (QT + 1) * DK; i += 256) {
        int q = i >> 6, d = i & 63;
        int qrow = q0 + q;
        float qq = (qrow < TT) ? bf2f(Q[base + (size_t)qrow * DK + d]) : 0.0f;
        qv[q][d] = qq + ldin(vbias, uvoff + h * DK + d, f32);
        if (q < QT) qu[q][d] = qq + ldin(ubias, uvoff + h * DK + d, f32);
    }
    __syncthreads();

    for (int j = tid; j < TT; j += 256) {
        unsigned long long pr[16];
        const unsigned long long* prow = (const unsigned long long*)(P + base + (size_t)j * DK);
        #pragma unroll
        for (int w = 0; w < 16; ++w) pr[w] = prow[w];
        for (int q = 0; q <= QT; ++q) {
            const float* qr = qv[q];
            float acc = 0.0f;
            #pragma unroll
            for (int w = 0; w < 16; ++w) {
                unsigned long long u = pr[w];
                acc += qr[4 * w + 0] * us2f((unsigned short)(u));
                acc += qr[4 * w + 1] * us2f((unsigned short)(u >> 16));
                acc += qr[4 * w + 2] * us2f((unsigned short)(u >> 32));
                acc += qr[4 * w + 3] * us2f((unsigned short)(u >> 48));
            }
            PS[q][j] = acc;
        }
    }
    __syncthreads();

    for (int k = tid; k < TT; k += 256) {
        unsigned long long kr[16];
        const unsigned long long* krow = (const unsigned long long*)(Kb + base + (size_t)k * DK);
        #pragma unroll
        for (int w = 0; w < 16; ++w) kr[w] = krow[w];
        for (int q = 0; q < QT; ++q) {
            const float* qr = qu[q];
            float acc = 0.0f;
            #pragma unroll
            for (int w = 0; w < 16; ++w) {
                unsigned long long u = kr[w];
                acc += qr[4 * w + 0] * us2f((unsigned short)(u));
                acc += qr[4 * w + 1] * us2f((unsigned short)(u >> 16));
                acc += qr[4 * w + 2] * us2f((unsigned short)(u >> 32));
                acc += qr[4 * w + 3] * us2f((unsigned short)(u >> 48));
            }
            int qr_ = q0 + q;
            float ps;
            if (k <= qr_)            ps = PS[q][k - qr_ + TT - 1];
            else if (k == qr_ + 1)   ps = 0.0f;
            else                     ps = PS[q + 1][k - qr_ - 2];
            S[q][k] = (acc + ps) * scale;
        }
    }
    __syncthreads();

    {
        const int q = tid >> 3, k0 = tid & 7;
        float m = -1e30f;
        for (int k = k0; k < TT; k += 8) m = fmaxf(m, S[q][k]);
        #pragma unroll
        for (int msk = 1; msk < 8; msk <<= 1) m = fmaxf(m, __shfl_xor(m, msk));
        float sum = 0.0f;
        for (int k = k0; k < TT; k += 8) {
            float e = __expf(S[q][k] - m);
            S[q][k] = e;
            sum += e;
        }
        #pragma unroll
        for (int msk = 1; msk < 8; msk <<= 1) sum += __shfl_xor(sum, msk);
        if (k0 == 0) rowinv[q] = 1.0f / sum;
    }
    __syncthreads();

    {
        const int d = tid & 63;
        const int strip = tid >> 6;
        float acc[8] = {};
        for (int k = 0; k < TT; ++k) {
            float v = bf2f(V[base + (size_t)k * DK + d]);
            #pragma unroll
            for (int qq = 0; qq < 8; ++qq)
                acc[qq] += S[strip * 8 + qq][k] * v;
        }
        #pragma unroll
        for (int qq = 0; qq < 8; ++qq) {
            int q = strip * 8 + qq, qrow = q0 + q;
            if (qrow < TT)
                ctx[((size_t)b * TT + qrow) * DD + h * DK + d] = f2bf(acc[qq] * rowinv[q]);
        }
    }
}

// ---------------------------------------------------------------------------
extern "C" void kernel_launch(void* const* d_in, const int* in_sizes, int n_in,
                              void* d_out, int out_size, void* d_ws, size_t ws_size,
                              hipStream_t stream)
{
    (void)in_sizes; (void)n_in; (void)out_size;
    const void* x    = d_in[0];
    const void* mask = d_in[1];
    const void* pos  = d_in[2];
    const void* Wq   = d_in[3];
    const void* bq   = d_in[4];
    const void* Wk   = d_in[5];
    const void* bk   = d_in[6];
    const void* Wv   = d_in[7];
    const void* bv   = d_in[8];
    const void* Wp   = d_in[9];
    const void* ub   = d_in[10];
    const void* vbi  = d_in[11];
    const void* Wo   = d_in[12];
    const void* bo   = d_in[13];
    const void* l1a  = d_in[14];
    const void* l1b  = d_in[15];
    const void* l2a  = d_in[16];
    const void* l2b  = d_in[17];
    const void* W1   = d_in[18];
    const void* b1   = d_in[19];
    const void* W2   = d_in[20];
    const void* b2   = d_in[21];
    const void* fa   = d_in[22];
    const void* fb   = d_in[23];

    const size_t exf = (size_t)MT * DD;
    char* w = (char*)d_ws;
    int*   dflag = (int*)w;
    float* xf = (float*)(w + 256);
    bf16*  xn = (bf16*)(w + 256 + exf * 4);
    bf16*  sc = (bf16*)(w + 256 + exf * 6);
    bf16*  wbuf = (bf16*)d_out;   // weights (20.4MB) live in d_out until final LN

    // runtime chunk selection from ws_size
    const size_t fixed = 256 + exf * 6;
    int cha = 8;
    if      (ws_size >= fixed + (size_t)4 * 64 * TT * DD * 2) cha = 64;
    else if (ws_size >= fixed + (size_t)4 * 32 * TT * DD * 2) cha = 32;
    else if (ws_size >= fixed + (size_t)4 * 16 * TT * DD * 2) cha = 16;
    const int nca = BB / cha;
    const int ma  = cha * TT;
    const int chf = (cha * 2 > 64) ? 64 : cha * 2;
    const int ncf = BB / chf;
    const int mf  = chf * TT;
    const int chN = ma * DD;

    bf16* qc = sc;
    bf16* pc = sc + (size_t)3 * chN;
    bf16* hb = sc;

    dim3 blk(256);
    dim3 g_ep((MT * DD + 255) / 256);
    dim3 g_ln(MT);
    dim3 g_qkv(12, (ma + 127) / 128);
    dim3 g_p(4, (ma + 127) / 128);
    dim3 g_attn(NQT, HH, cha);
    dim3 g_o(4, (MT + 127) / 128);
    dim3 g_f1(8, (mf + 127) / 128);
    dim3 g_cv(4, (mf + 127) / 128);

    detect_kernel<<<dim3(1), dim3(64), 0, stream>>>((const unsigned short*)l1a, dflag);

    // convert weights (all layers) into d_out scratch
    auto cvt = [&](const void* src, size_t S, size_t doff, int mode) {
        dim3 g((unsigned)(((size_t)3 * S + 255) / 256));
        cvt_kernel<<<g, blk, 0, stream>>>(src, S, S, wbuf, doff, 3, mode, dflag);
    };
    cvt(Wq, 262144, OFF_QKV,          0);
    cvt(Wk, 262144, OFF_QKV + 262144, 0);
    cvt(Wv, 262144, OFF_QKV + 524288, 0);
    cvt(Wp, 262144, OFF_P,            0);
    cvt(Wo, 262144, OFF_O,            0);
    cvt(W1, 524288, OFF_W1,           0);
    cvt(W2, 1572864, OFF_W2,          1);

    for (int l = 0; l < LL; ++l) {
        const bf16* wl = wbuf + (size_t)l * LW;
        addpos_kernel<<<g_ep, blk, 0, stream>>>(x, pos, (size_t)l * TD, xf, l == 0, dflag);
        ln_kernel<<<g_ln, blk, 0, stream>>>(xf, l1a, (size_t)l * DD, l1b, (size_t)l * DD, xn, 0, dflag);
        for (int c = 0; c < nca; ++c) {
            bf16* xnc = xn + (size_t)c * ma * DD;
            mgemm_kernel<<<g_qkv, blk, 0, stream>>>(xnc, 0, 0, wl + OFF_QKV,
                bq, bk, bv, (size_t)l * DD, qc, ma, 1536, DD, 0, chN, dflag);
            mgemm_kernel<<<g_p, blk, 0, stream>>>(mask, (size_t)c * ma * DD, 1, wl + OFF_P,
                nullptr, nullptr, nullptr, 0, pc, ma, DD, DD, 0, 0, dflag);
            attn_kernel<<<g_attn, blk, 0, stream>>>(qc, qc + chN, qc + 2 * (size_t)chN, pc,
                ub, vbi, (size_t)l * HH * DK, xnc, dflag);
        }
        mgemm_kernel<<<g_o, blk, 0, stream>>>(xn, 0, 0, wl + OFF_O,
            bo, nullptr, nullptr, (size_t)l * DD, xf, MT, DD, DD, 2, 0, dflag);
        ln_kernel<<<g_ln, blk, 0, stream>>>(xf, l2a, (size_t)l * DD, l2b, (size_t)l * DD, xn, 0, dflag);
        for (int c = 0; c < ncf; ++c) {
            mgemm_kernel<<<g_f1, blk, 0, stream>>>(xn + (size_t)c * mf * DD, 0, 0, wl + OFF_W1,
                b1, nullptr, nullptr, (size_t)l * FF, hb, mf, FF, DD, 1, 0, dflag);
            mconv_kernel<<<g_cv, blk, 0, stream>>>(hb, wl + OFF_W2,
                b2, (size_t)l * DD, xf + (size_t)c * mf * DD, mf, dflag);
        }
    }
    ln_kernel<<<g_ln, blk, 0, stream>>>(xf, fa, 0, fb, 0, d_out, 1, dflag);
}